// Round 4
// baseline (237.446 us; speedup 1.0000x reference)
//
#include <hip/hip_runtime.h>
#include <hip/hip_bf16.h>

typedef unsigned short ushort_t;
typedef __attribute__((ext_vector_type(4))) float v4f;
typedef __attribute__((ext_vector_type(8))) short v8s;

#define FDIM 128
#define KCLUST 16
#define CSTRIDE 264   // combined-row stride in bf16 elems (264*2B = 528B)

__device__ __forceinline__ ushort_t f2bf(float x) {
    unsigned int u = __float_as_uint(x);
    unsigned int r = (u + 0x7fffu + ((u >> 16) & 1u)) >> 16;
    return (ushort_t)r;
}
__device__ __forceinline__ float bf2f(ushort_t h) {
    return __uint_as_float((unsigned int)h << 16);
}

union V8U { v8s v; ushort_t u[8]; };

// ---------------------------------------------------------------------------
// Kernel 1: cast weight (E x 256 f32) -> bf16, padded to Np rows (zeros).
// ---------------------------------------------------------------------------
__global__ void pack_weight(const float* __restrict__ W, ushort_t* __restrict__ Wb,
                            long total, long valid) {
    long i = ((long)blockIdx.x * blockDim.x + threadIdx.x) * 4;
    if (i >= total) return;
    float4 v;
    if (i < valid) v = *(const float4*)(W + i);
    else           v = make_float4(0.f, 0.f, 0.f, 0.f);
    ushort_t* dst = Wb + i;
    dst[0] = f2bf(v.x); dst[1] = f2bf(v.y); dst[2] = f2bf(v.z); dst[3] = f2bf(v.w);
}

// ---------------------------------------------------------------------------
// Kernel 2 (fused), v5: counted-wait barriers + no wave0 serialization.
//   v4's loop had 2 __syncthreads per s; each drains vmcnt(0) -> the s+1
//   neighbor-gather prefetch (issued ~200cy earlier) stalls the whole block
//   for its full ~800cy HBM latency, every iteration. v5:
//   - ONE raw s_barrier per s, preceded only by s_waitcnt lgkmcnt(0):
//     cross-thread deps in the loop are LDS-only; the global prefetch stays
//     in flight across the barrier (consumed thread-privately next s).
//   - barrier 2 removed: EVERY wave computes cross[16,16] via 4 MFMA
//     (redundant; MFMA pipe was 4% busy) + q, then transposes q through its
//     OWN per-wave LDS buffer (wave-local lgkm wait, no block barrier).
//   - parity double-buffer makes 1-barrier/s race-free: stage[s+1] (buf^1)
//     can only start after barrier[s], which requires all compute[s-1]
//     (the previous reader of buf^1) to have finished.
// ---------------------------------------------------------------------------
__global__ __launch_bounds__(512, 2) void fused_agg(
    const int* __restrict__ nodes, const int* __restrict__ neigh_idx,
    const float* __restrict__ self_table, const float* __restrict__ neigh_table,
    const float* __restrict__ center, const float* __restrict__ cluster_mask,
    const float* __restrict__ alpha, const ushort_t* __restrict__ Wb,
    float* __restrict__ out, int B, int S, int E) {

    __shared__ __align__(16) ushort_t comb[16 * CSTRIDE];     // 8448 B
    __shared__ __align__(16) ushort_t nbf[2][16 * 128];       // 8192 B (swizzled bf16 N)
    __shared__ __align__(16) float    nf32[2][16 * 132];      // 16896 B (f32 N, pad 132)
    __shared__ __align__(16) float    attL[2][16];
    __shared__ __align__(16) float    n2L[2][16];
    __shared__ __align__(16) ushort_t qhi[8][256];            // per-wave 512 B
    __shared__ __align__(16) ushort_t qlo[8][256];            // per-wave 512 B
    __shared__ __align__(16) float    invL[16];

    const int t    = threadIdx.x;
    const int lane = t & 63, wave = t >> 6;   // 8 waves
    const int row  = t >> 5;                  // 0..15 (2 rows per wave)
    const int fq   = t & 31;                  // feat-quad within row
    const int f0   = fq << 2;                 // first of this thread's 4 feats
    const int l16  = lane & 15, quad = lane >> 4;

    const int b0 = blockIdx.x * 16;
    int b = b0 + row; if (b >= B) b = B - 1;  // clamp loads; stores guarded

    const float4 aS = *(const float4*)(alpha + f0);
    const float4 aN = *(const float4*)(alpha + FDIM + f0);

    // ---- self features: stage to comb (bf16) + logit_self butterfly ----
    float ls;
    {
        size_t node = (size_t)nodes[b];
        float4 sf = *(const float4*)(self_table + node * FDIM + f0);
        ushort_t h0 = f2bf(sf.x), h1 = f2bf(sf.y), h2 = f2bf(sf.z), h3 = f2bf(sf.w);
        uint2 pk;
        pk.x = (unsigned)h0 | ((unsigned)h1 << 16);
        pk.y = (unsigned)h2 | ((unsigned)h3 << 16);
        *(uint2*)(comb + row * CSTRIDE + f0) = pk;
        ls = sf.x * aS.x + sf.y * aS.y + sf.z * aS.z + sf.w * aS.w;
        #pragma unroll
        for (int off = 1; off <= 16; off <<= 1) ls += __shfl_xor(ls, off, 64);
    }

    // ---- ALL waves: center B-fragments (bf16) + c2 (exact f32) ----
    v8s cbf[4]; float c2v = 0.f;
    {
        const float* crow = center + l16 * FDIM;
        #pragma unroll
        for (int kk = 0; kk < 4; kk++) {
            const float* p = crow + kk * 32 + quad * 8;
            float4 x = *(const float4*)p;
            float4 y = *(const float4*)(p + 4);
            V8U pk;
            pk.u[0] = f2bf(x.x); pk.u[1] = f2bf(x.y); pk.u[2] = f2bf(x.z); pk.u[3] = f2bf(x.w);
            pk.u[4] = f2bf(y.x); pk.u[5] = f2bf(y.y); pk.u[6] = f2bf(y.z); pk.u[7] = f2bf(y.w);
            cbf[kk] = pk.v;
            c2v += x.x*x.x + x.y*x.y + x.z*x.z + x.w*x.w
                 + y.x*y.x + y.y*y.y + y.z*y.z + y.w*y.w;
        }
        c2v += __shfl_xor(c2v, 16, 64);   // reduce across quads
        c2v += __shfl_xor(c2v, 32, 64);
    }

    // ---- mask B-fragments for this wave's 16-feature tile (split bf16) ----
    v8s mhi, mlo;
    {
        V8U ph, pl;
        const int fcol = wave * 16 + l16;   // 8 waves * 16 = 128 = FDIM
        #pragma unroll
        for (int j = 0; j < 8; j++) {
            float mv = (quad < 2) ? cluster_mask[(quad * 8 + j) * FDIM + fcol] : 0.f;
            ushort_t h = f2bf(mv);
            ph.u[j] = h;
            pl.u[j] = f2bf(mv - bf2f(h));
        }
        mhi = ph.v; mlo = pl.v;
    }

    // ---- neighbor gather pipeline ----
    int idx0 = neigh_idx[(size_t)b * S];
    float4 n4 = *(const float4*)(neigh_table + (size_t)idx0 * FDIM + f0);
    int idx_next = (S > 1) ? neigh_idx[(size_t)b * S + 1] : 0;

    float attsum = 0.f;
    float acc0 = 0.f, acc1 = 0.f, acc2 = 0.f, acc3 = 0.f;  // rows quad*4+r, col wave*16+l16

    for (int s = 0; s < S; s++) {
        const int buf = s & 1;
        const float4 cur = n4;
        if (s + 1 < S) {
            n4 = *(const float4*)(neigh_table + (size_t)idx_next * FDIM + f0);
            if (s + 2 < S) idx_next = neigh_idx[(size_t)b * S + s + 2];
        }

        // stage f32 N
        *(float4*)(nf32[buf] + row * 132 + f0) = cur;
        // stage bf16 N, XOR-swizzled 16B slots (conflict-free A-frag reads)
        {
            ushort_t h0 = f2bf(cur.x), h1 = f2bf(cur.y), h2 = f2bf(cur.z), h3 = f2bf(cur.w);
            uint2 pk;
            pk.x = (unsigned)h0 | ((unsigned)h1 << 16);
            pk.y = (unsigned)h2 | ((unsigned)h3 << 16);
            const int slot = (fq >> 1) ^ (row & 15);
            *(uint2*)((char*)(nbf[buf]) + row * 256 + slot * 16 + (fq & 1) * 8) = pk;
        }
        // logit + n2 butterflies (within each row's 32 lanes)
        float pn = cur.x * aN.x + cur.y * aN.y + cur.z * aN.z + cur.w * aN.w;
        float p2 = cur.x * cur.x + cur.y * cur.y + cur.z * cur.z + cur.w * cur.w;
        #pragma unroll
        for (int off = 1; off <= 16; off <<= 1) {
            pn += __shfl_xor(pn, off, 64);
            p2 += __shfl_xor(p2, off, 64);
        }
        const float att = __expf(fmaxf(ls + pn, 0.f));
        attsum += att;
        if (fq == 0) { attL[buf][row] = att; n2L[buf][row] = p2; }

        // ---- barrier: LDS drains only; global prefetch stays in flight ----
        asm volatile("s_waitcnt lgkmcnt(0)" ::: "memory");
        __builtin_amdgcn_s_barrier();
        asm volatile("" ::: "memory");   // fence against hoisting LDS reads above

        // ---- every wave: cross[16,16] via 4 MFMA + q (redundant, barrier-free) ----
        v4f xacc = {0.f, 0.f, 0.f, 0.f};
        #pragma unroll
        for (int kk = 0; kk < 4; kk++) {
            const int sl = (kk * 4 + quad) ^ l16;
            v8s af = *(const v8s*)((char*)(nbf[buf]) + l16 * 256 + sl * 16);
            xacc = __builtin_amdgcn_mfma_f32_16x16x32_bf16(af, cbf[kk], xacc, 0, 0, 0);
        }
        const float4 n2r = *(const float4*)(&n2L[buf][quad * 4]);
        ushort_t* const qh = qhi[wave];
        ushort_t* const ql = qlo[wave];
        #pragma unroll
        for (int r = 0; r < 4; r++) {
            const float n2v = (r == 0) ? n2r.x : (r == 1) ? n2r.y : (r == 2) ? n2r.z : n2r.w;
            const float d  = n2v - 2.f * xacc[r] + c2v;
            const float qv = 1.f / (d + 1.f);
            const ushort_t h = f2bf(qv);
            qh[(quad * 4 + r) * 16 + l16] = h;
            ql[(quad * 4 + r) * 16 + l16] = f2bf(qv - bf2f(h));
        }
        // wave-local transpose round-trip: only this wave's lgkm must drain
        asm volatile("s_waitcnt lgkmcnt(0)" ::: "memory");
        __builtin_amdgcn_sched_barrier(0);
        // quads 2,3 mirror quads 0,1 (B-frag rows k>=16 are zero -> products 0)
        v8s aqh = *(const v8s*)((char*)qh + l16 * 32 + (quad & 1) * 16);
        v8s aql = *(const v8s*)((char*)ql + l16 * 32 + (quad & 1) * 16);
        v4f mac = {0.f, 0.f, 0.f, 0.f};
        mac = __builtin_amdgcn_mfma_f32_16x16x32_bf16(aqh, mhi, mac, 0, 0, 0);
        mac = __builtin_amdgcn_mfma_f32_16x16x32_bf16(aql, mhi, mac, 0, 0, 0);
        mac = __builtin_amdgcn_mfma_f32_16x16x32_bf16(aqh, mlo, mac, 0, 0, 0);

        // accumulate att * n * m in f32 (D-layout: rows quad*4+r, col wave*16+l16)
        const float4 attr = *(const float4*)(&attL[buf][quad * 4]);
        const float* nfp = nf32[buf] + wave * 16 + l16;
        acc0 = fmaf(attr.x * mac[0], nfp[(quad * 4 + 0) * 132], acc0);
        acc1 = fmaf(attr.y * mac[1], nfp[(quad * 4 + 1) * 132], acc1);
        acc2 = fmaf(attr.z * mac[2], nfp[(quad * 4 + 2) * 132], acc2);
        acc3 = fmaf(attr.w * mac[3], nfp[(quad * 4 + 3) * 132], acc3);
    }

    // ---- normalize + write neigh-agg half of comb ----
    if (fq == 0) invL[row] = 1.f / attsum;
    __syncthreads();
    {
        const float4 invr = *(const float4*)(&invL[quad * 4]);
        ushort_t* cp = comb + 128 + wave * 16 + l16;
        cp[(quad * 4 + 0) * CSTRIDE] = f2bf(acc0 * invr.x);
        cp[(quad * 4 + 1) * CSTRIDE] = f2bf(acc1 * invr.y);
        cp[(quad * 4 + 2) * CSTRIDE] = f2bf(acc2 * invr.z);
        cp[(quad * 4 + 3) * CSTRIDE] = f2bf(acc3 * invr.w);
    }

    // ---------------- phase B: out[16][E] = relu(comb @ Wb^T) ----------------
    const int Ntiles = (E + 15) >> 4;

    // prefetch this wave's first W tile before the barrier (hides L2 latency)
    v8s bfr[8];
    {
        const int nt0 = (wave < Ntiles) ? wave : 0;
        const ushort_t* wrow = Wb + (size_t)(nt0 * 16 + l16) * 256 + quad * 8;
        #pragma unroll
        for (int kk = 0; kk < 8; kk++)
            bfr[kk] = *(const v8s*)(wrow + kk * 32);
    }

    __syncthreads();

    // A-fragments: A[m=l16][k = kk*32 + quad*8 + j]
    v8s afr[8];
    #pragma unroll
    for (int kk = 0; kk < 8; kk++)
        afr[kk] = *(const v8s*)(comb + l16 * CSTRIDE + kk * 32 + quad * 8);

    for (int nt = wave; nt < Ntiles; nt += 8) {
        if (nt != wave) {
            const ushort_t* wrow = Wb + (size_t)(nt * 16 + l16) * 256 + quad * 8;
            #pragma unroll
            for (int kk = 0; kk < 8; kk++)
                bfr[kk] = *(const v8s*)(wrow + kk * 32);
        }
        v4f acc = {0.f, 0.f, 0.f, 0.f};
        #pragma unroll
        for (int kk = 0; kk < 8; kk++)
            acc = __builtin_amdgcn_mfma_f32_16x16x32_bf16(afr[kk], bfr[kk], acc, 0, 0, 0);
        const int gcol = nt * 16 + l16;
        if (gcol < E) {
            #pragma unroll
            for (int rr = 0; rr < 4; rr++) {
                const int grow = b0 + quad * 4 + rr;
                if (grow < B)
                    out[(size_t)grow * E + gcol] = fmaxf(acc[rr], 0.f);
            }
        }
    }
}

extern "C" void kernel_launch(void* const* d_in, const int* in_sizes, int n_in,
                              void* d_out, int out_size, void* d_ws, size_t ws_size,
                              hipStream_t stream) {
    const int*   nodes        = (const int*)d_in[0];
    const int*   neigh_idx    = (const int*)d_in[1];
    const float* self_table   = (const float*)d_in[2];
    const float* neigh_table  = (const float*)d_in[3];
    const float* center       = (const float*)d_in[4];
    const float* cluster_mask = (const float*)d_in[5];
    const float* weight       = (const float*)d_in[6];
    const float* alpha        = (const float*)d_in[7];
    float* out = (float*)d_out;

    int B = in_sizes[0];
    int S = in_sizes[1] / B;
    int E = in_sizes[6] / (2 * FDIM);

    int Np = ((E + 15) / 16) * 16;
    ushort_t* Wb = (ushort_t*)d_ws;   // Np x 256 bf16

    long totalW = (long)Np * 256;
    long validW = (long)E * 256;
    int blksW = (int)((totalW + 1023) / 1024);
    pack_weight<<<blksW, 256, 0, stream>>>(weight, Wb, totalW, validW);

    int nblk = (B + 15) / 16;
    fused_agg<<<nblk, 512, 0, stream>>>(
        nodes, neigh_idx, self_table, neigh_table, center, cluster_mask, alpha,
        Wb, out, B, S, E);
}

// Round 5
// 232.278 us; speedup vs baseline: 1.0222x; 1.0222x over previous
//
#include <hip/hip_runtime.h>
#include <hip/hip_bf16.h>

typedef unsigned short ushort_t;
typedef __attribute__((ext_vector_type(4))) float v4f;
typedef __attribute__((ext_vector_type(8))) short v8s;

#define FDIM 128
#define KCLUST 16
#define CSTRIDE 264   // combined-row stride in bf16 elems (264*2B = 528B)
#define QSTRIDE 24    // q row stride in shorts (48B): 2-way banks instead of 4-way

__device__ __forceinline__ ushort_t f2bf(float x) {
    unsigned int u = __float_as_uint(x);
    unsigned int r = (u + 0x7fffu + ((u >> 16) & 1u)) >> 16;
    return (ushort_t)r;
}
__device__ __forceinline__ float bf2f(ushort_t h) {
    return __uint_as_float((unsigned int)h << 16);
}

union V8U { v8s v; ushort_t u[8]; };

// ---------------------------------------------------------------------------
// Kernel 1: cast weight (E x 256 f32) -> bf16, padded to Np rows (zeros).
// ---------------------------------------------------------------------------
__global__ void pack_weight(const float* __restrict__ W, ushort_t* __restrict__ Wb,
                            long total, long valid) {
    long i = ((long)blockIdx.x * blockDim.x + threadIdx.x) * 4;
    if (i >= total) return;
    float4 v;
    if (i < valid) v = *(const float4*)(W + i);
    else           v = make_float4(0.f, 0.f, 0.f, 0.f);
    ushort_t* dst = Wb + i;
    dst[0] = f2bf(v.x); dst[1] = f2bf(v.y); dst[2] = f2bf(v.z); dst[3] = f2bf(v.w);
}

// ---------------------------------------------------------------------------
// Kernel 2 (fused), v6: v4 structure (wave0-only cross+q, 2 barriers/s)
//   with v5's raw lgkm-only barriers. v5 proved the barrier machinery
//   correct but added 8x-redundant q VALU (+15us VALU time, 3.7x bank
//   conflicts). v6 isolates the barrier-drain fix on the lean structure:
//   - both per-s barriers are  s_waitcnt lgkmcnt(0); s_barrier  -> the s+1
//     neighbor gather (vmcnt) stays in flight across them; its HBM/LLC
//     latency hides under a full iteration instead of stalling the block.
//   - qhi/qlo rows padded to 48B: q A-frag read drops 4-way -> 2-way (free).
// ---------------------------------------------------------------------------
__global__ __launch_bounds__(512, 2) void fused_agg(
    const int* __restrict__ nodes, const int* __restrict__ neigh_idx,
    const float* __restrict__ self_table, const float* __restrict__ neigh_table,
    const float* __restrict__ center, const float* __restrict__ cluster_mask,
    const float* __restrict__ alpha, const ushort_t* __restrict__ Wb,
    float* __restrict__ out, int B, int S, int E) {

    __shared__ __align__(16) ushort_t comb[16 * CSTRIDE];     // 8448 B
    __shared__ __align__(16) ushort_t nbf[2][16 * 128];       // 8192 B (swizzled bf16 N)
    __shared__ __align__(16) float    nf32[2][16 * 132];      // 16896 B (f32 N, pad 132)
    __shared__ __align__(16) float    attL[2][16];
    __shared__ __align__(16) float    n2L[2][16];
    __shared__ __align__(16) ushort_t qhi[16 * QSTRIDE];      // 768 B
    __shared__ __align__(16) ushort_t qlo[16 * QSTRIDE];      // 768 B
    __shared__ __align__(16) float    invL[16];

    const int t    = threadIdx.x;
    const int lane = t & 63, wave = t >> 6;   // 8 waves
    const int row  = t >> 5;                  // 0..15 (2 rows per wave)
    const int fq   = t & 31;                  // feat-quad within row
    const int f0   = fq << 2;                 // first of this thread's 4 feats
    const int l16  = lane & 15, quad = lane >> 4;

    const int b0 = blockIdx.x * 16;
    int b = b0 + row; if (b >= B) b = B - 1;  // clamp loads; stores guarded

    const float4 aS = *(const float4*)(alpha + f0);
    const float4 aN = *(const float4*)(alpha + FDIM + f0);

    // ---- self features: stage to comb (bf16) + logit_self butterfly ----
    float ls;
    {
        size_t node = (size_t)nodes[b];
        float4 sf = *(const float4*)(self_table + node * FDIM + f0);
        ushort_t h0 = f2bf(sf.x), h1 = f2bf(sf.y), h2 = f2bf(sf.z), h3 = f2bf(sf.w);
        uint2 pk;
        pk.x = (unsigned)h0 | ((unsigned)h1 << 16);
        pk.y = (unsigned)h2 | ((unsigned)h3 << 16);
        *(uint2*)(comb + row * CSTRIDE + f0) = pk;
        ls = sf.x * aS.x + sf.y * aS.y + sf.z * aS.z + sf.w * aS.w;
        #pragma unroll
        for (int off = 1; off <= 16; off <<= 1) ls += __shfl_xor(ls, off, 64);
    }

    // ---- wave 0: center B-fragments (bf16) + c2 (exact f32) ----
    v8s cbf[4]; float c2v = 0.f;
    if (wave == 0) {
        const float* crow = center + l16 * FDIM;
        #pragma unroll
        for (int kk = 0; kk < 4; kk++) {
            const float* p = crow + kk * 32 + quad * 8;
            float4 x = *(const float4*)p;
            float4 y = *(const float4*)(p + 4);
            V8U pk;
            pk.u[0] = f2bf(x.x); pk.u[1] = f2bf(x.y); pk.u[2] = f2bf(x.z); pk.u[3] = f2bf(x.w);
            pk.u[4] = f2bf(y.x); pk.u[5] = f2bf(y.y); pk.u[6] = f2bf(y.z); pk.u[7] = f2bf(y.w);
            cbf[kk] = pk.v;
            c2v += x.x*x.x + x.y*x.y + x.z*x.z + x.w*x.w
                 + y.x*y.x + y.y*y.y + y.z*y.z + y.w*y.w;
        }
        c2v += __shfl_xor(c2v, 16, 64);   // reduce across quads
        c2v += __shfl_xor(c2v, 32, 64);
    }

    // ---- mask B-fragments for this wave's 16-feature tile (split bf16) ----
    v8s mhi, mlo;
    {
        V8U ph, pl;
        const int fcol = wave * 16 + l16;   // 8 waves * 16 = 128 = FDIM
        #pragma unroll
        for (int j = 0; j < 8; j++) {
            float mv = (quad < 2) ? cluster_mask[(quad * 8 + j) * FDIM + fcol] : 0.f;
            ushort_t h = f2bf(mv);
            ph.u[j] = h;
            pl.u[j] = f2bf(mv - bf2f(h));
        }
        mhi = ph.v; mlo = pl.v;
    }

    // ---- neighbor gather pipeline ----
    int idx0 = neigh_idx[(size_t)b * S];
    float4 n4 = *(const float4*)(neigh_table + (size_t)idx0 * FDIM + f0);
    int idx_next = (S > 1) ? neigh_idx[(size_t)b * S + 1] : 0;

    float attsum = 0.f;
    float acc0 = 0.f, acc1 = 0.f, acc2 = 0.f, acc3 = 0.f;  // rows quad*4+r, col wave*16+l16

    for (int s = 0; s < S; s++) {
        const int buf = s & 1;
        const float4 cur = n4;
        if (s + 1 < S) {
            n4 = *(const float4*)(neigh_table + (size_t)idx_next * FDIM + f0);
            if (s + 2 < S) idx_next = neigh_idx[(size_t)b * S + s + 2];
        }

        // stage f32 N
        *(float4*)(nf32[buf] + row * 132 + f0) = cur;
        // stage bf16 N, XOR-swizzled 16B slots (conflict-free A-frag reads)
        {
            ushort_t h0 = f2bf(cur.x), h1 = f2bf(cur.y), h2 = f2bf(cur.z), h3 = f2bf(cur.w);
            uint2 pk;
            pk.x = (unsigned)h0 | ((unsigned)h1 << 16);
            pk.y = (unsigned)h2 | ((unsigned)h3 << 16);
            const int slot = (fq >> 1) ^ (row & 15);
            *(uint2*)((char*)(nbf[buf]) + row * 256 + slot * 16 + (fq & 1) * 8) = pk;
        }
        // logit + n2 butterflies (within each row's 32 lanes)
        float pn = cur.x * aN.x + cur.y * aN.y + cur.z * aN.z + cur.w * aN.w;
        float p2 = cur.x * cur.x + cur.y * cur.y + cur.z * cur.z + cur.w * cur.w;
        #pragma unroll
        for (int off = 1; off <= 16; off <<= 1) {
            pn += __shfl_xor(pn, off, 64);
            p2 += __shfl_xor(p2, off, 64);
        }
        const float att = __expf(fmaxf(ls + pn, 0.f));
        attsum += att;
        if (fq == 0) { attL[buf][row] = att; n2L[buf][row] = p2; }

        // ---- barrier 1: LDS drains only; global prefetch stays in flight ----
        asm volatile("s_waitcnt lgkmcnt(0)" ::: "memory");
        __builtin_amdgcn_s_barrier();
        asm volatile("" ::: "memory");

        if (wave == 0) {
            // cross[row][k] = sum_f N[row][f] * center[k][f], 4 MFMA over K=128
            v4f xacc = {0.f, 0.f, 0.f, 0.f};
            #pragma unroll
            for (int kk = 0; kk < 4; kk++) {
                const int sl = (kk * 4 + quad) ^ l16;
                v8s af = *(const v8s*)((char*)(nbf[buf]) + l16 * 256 + sl * 16);
                xacc = __builtin_amdgcn_mfma_f32_16x16x32_bf16(af, cbf[kk], xacc, 0, 0, 0);
            }
            const float4 n2r = *(const float4*)(&n2L[buf][quad * 4]);
            #pragma unroll
            for (int r = 0; r < 4; r++) {
                const float n2v = (r == 0) ? n2r.x : (r == 1) ? n2r.y : (r == 2) ? n2r.z : n2r.w;
                const float d  = n2v - 2.f * xacc[r] + c2v;
                const float qv = 1.f / (d + 1.f);
                const ushort_t h = f2bf(qv);
                qhi[(quad * 4 + r) * QSTRIDE + l16] = h;
                qlo[(quad * 4 + r) * QSTRIDE + l16] = f2bf(qv - bf2f(h));
            }
        }

        // ---- barrier 2: q ready (lgkm-only again; vmem stays in flight) ----
        asm volatile("s_waitcnt lgkmcnt(0)" ::: "memory");
        __builtin_amdgcn_s_barrier();
        asm volatile("" ::: "memory");

        // m-tile: m[row][wave*16+l16] = sum_k q[row][k]*mask[k][f]
        // quads 2,3 mirror quads 0,1 (same addr = broadcast; B rows k>=16 zero)
        v8s aqh = *(const v8s*)(qhi + l16 * QSTRIDE + (quad & 1) * 8);
        v8s aql = *(const v8s*)(qlo + l16 * QSTRIDE + (quad & 1) * 8);
        v4f mac = {0.f, 0.f, 0.f, 0.f};
        mac = __builtin_amdgcn_mfma_f32_16x16x32_bf16(aqh, mhi, mac, 0, 0, 0);
        mac = __builtin_amdgcn_mfma_f32_16x16x32_bf16(aql, mhi, mac, 0, 0, 0);
        mac = __builtin_amdgcn_mfma_f32_16x16x32_bf16(aqh, mlo, mac, 0, 0, 0);

        // accumulate att * n * m in f32 (D-layout: rows quad*4+r, col wave*16+l16)
        const float4 attr = *(const float4*)(&attL[buf][quad * 4]);
        const float* nfp = nf32[buf] + wave * 16 + l16;
        acc0 = fmaf(attr.x * mac[0], nfp[(quad * 4 + 0) * 132], acc0);
        acc1 = fmaf(attr.y * mac[1], nfp[(quad * 4 + 1) * 132], acc1);
        acc2 = fmaf(attr.z * mac[2], nfp[(quad * 4 + 2) * 132], acc2);
        acc3 = fmaf(attr.w * mac[3], nfp[(quad * 4 + 3) * 132], acc3);
    }

    // ---- normalize + write neigh-agg half of comb ----
    if (fq == 0) invL[row] = 1.f / attsum;
    __syncthreads();
    {
        const float4 invr = *(const float4*)(&invL[quad * 4]);
        ushort_t* cp = comb + 128 + wave * 16 + l16;
        cp[(quad * 4 + 0) * CSTRIDE] = f2bf(acc0 * invr.x);
        cp[(quad * 4 + 1) * CSTRIDE] = f2bf(acc1 * invr.y);
        cp[(quad * 4 + 2) * CSTRIDE] = f2bf(acc2 * invr.z);
        cp[(quad * 4 + 3) * CSTRIDE] = f2bf(acc3 * invr.w);
    }

    // ---------------- phase B: out[16][E] = relu(comb @ Wb^T) ----------------
    const int Ntiles = (E + 15) >> 4;

    // prefetch this wave's first W tile before the barrier (hides L2 latency)
    v8s bfr[8];
    {
        const int nt0 = (wave < Ntiles) ? wave : 0;
        const ushort_t* wrow = Wb + (size_t)(nt0 * 16 + l16) * 256 + quad * 8;
        #pragma unroll
        for (int kk = 0; kk < 8; kk++)
            bfr[kk] = *(const v8s*)(wrow + kk * 32);
    }

    __syncthreads();

    // A-fragments: A[m=l16][k = kk*32 + quad*8 + j]
    v8s afr[8];
    #pragma unroll
    for (int kk = 0; kk < 8; kk++)
        afr[kk] = *(const v8s*)(comb + l16 * CSTRIDE + kk * 32 + quad * 8);

    for (int nt = wave; nt < Ntiles; nt += 8) {
        if (nt != wave) {
            const ushort_t* wrow = Wb + (size_t)(nt * 16 + l16) * 256 + quad * 8;
            #pragma unroll
            for (int kk = 0; kk < 8; kk++)
                bfr[kk] = *(const v8s*)(wrow + kk * 32);
        }
        v4f acc = {0.f, 0.f, 0.f, 0.f};
        #pragma unroll
        for (int kk = 0; kk < 8; kk++)
            acc = __builtin_amdgcn_mfma_f32_16x16x32_bf16(afr[kk], bfr[kk], acc, 0, 0, 0);
        const int gcol = nt * 16 + l16;
        if (gcol < E) {
            #pragma unroll
            for (int rr = 0; rr < 4; rr++) {
                const int grow = b0 + quad * 4 + rr;
                if (grow < B)
                    out[(size_t)grow * E + gcol] = fmaxf(acc[rr], 0.f);
            }
        }
    }
}

extern "C" void kernel_launch(void* const* d_in, const int* in_sizes, int n_in,
                              void* d_out, int out_size, void* d_ws, size_t ws_size,
                              hipStream_t stream) {
    const int*   nodes        = (const int*)d_in[0];
    const int*   neigh_idx    = (const int*)d_in[1];
    const float* self_table   = (const float*)d_in[2];
    const float* neigh_table  = (const float*)d_in[3];
    const float* center       = (const float*)d_in[4];
    const float* cluster_mask = (const float*)d_in[5];
    const float* weight       = (const float*)d_in[6];
    const float* alpha        = (const float*)d_in[7];
    float* out = (float*)d_out;

    int B = in_sizes[0];
    int S = in_sizes[1] / B;
    int E = in_sizes[6] / (2 * FDIM);

    int Np = ((E + 15) / 16) * 16;
    ushort_t* Wb = (ushort_t*)d_ws;   // Np x 256 bf16

    long totalW = (long)Np * 256;
    long validW = (long)E * 256;
    int blksW = (int)((totalW + 1023) / 1024);
    pack_weight<<<blksW, 256, 0, stream>>>(weight, Wb, totalW, validW);

    int nblk = (B + 15) / 16;
    fused_agg<<<nblk, 512, 0, stream>>>(
        nodes, neigh_idx, self_table, neigh_table, center, cluster_mask, alpha,
        Wb, out, B, S, E);
}